// Round 6
// baseline (116.951 us; speedup 1.0000x reference)
//
#include <hip/hip_runtime.h>
#include <math.h>

namespace {

constexpr int B   = 2048;
constexpr int L   = 200;
constexpr int E   = 96;    // 3 * D_FEAT
constexpr int U   = 64;
constexpr int NA  = 36;    // HID_ATT
constexpr int H1  = 200;
constexpr int H2  = 80;
constexpr int RB  = 8;     // rows per block in k_bcd
constexpr int NBLK = B / RB;   // 256 blocks = 1/CU -> co-residency guaranteed

__device__ __forceinline__ float sigf(float x) {
    return 1.0f / (1.0f + __expf(-x));
}

// ---------------------------------------------------------------------------
// K0: zero stats + barrier counters; fold the linear attention MLP.
// vbuf[0..95]=v1+v3 (mult q) | [96..191]=v2-v3 (mult ub) | [192..287]=v4 |
// [288] = w_att2·b_att1 + b_att2
// ---------------------------------------------------------------------------
__global__ void k_pre(const float* __restrict__ w_att1,
                      const float* __restrict__ b_att1,
                      const float* __restrict__ w_att2,
                      const float* __restrict__ b_att2,
                      float* __restrict__ stats,   // 768 floats
                      int*   __restrict__ bars,    // 64 ints (2 cache lines)
                      float* __restrict__ vbuf) {
    int j = threadIdx.x;               // 768 threads
    stats[j] = 0.f;
    if (j < 64) bars[j] = 0;
    if (j < 96) {
        float s = 0.f;
        #pragma unroll
        for (int k = 0; k < NA; ++k)
            s += w_att2[k] * (w_att1[k * 384 + j] + w_att1[k * 384 + 192 + j]);
        vbuf[j] = s;
    } else if (j < 192) {
        int e = j - 96; float s = 0.f;
        #pragma unroll
        for (int k = 0; k < NA; ++k)
            s += w_att2[k] * (w_att1[k * 384 + 96 + e] - w_att1[k * 384 + 192 + e]);
        vbuf[j] = s;
    } else if (j < 288) {
        int e = j - 192; float s = 0.f;
        #pragma unroll
        for (int k = 0; k < NA; ++k)
            s += w_att2[k] * w_att1[k * 384 + 288 + e];
        vbuf[j] = s;
    } else if (j == 288) {
        float c = b_att2[0];
        #pragma unroll
        for (int k = 0; k < NA; ++k) c += w_att2[k] * b_att1[k];
        vbuf[288] = c;
    }
}

// ---------------------------------------------------------------------------
// K1: one batch row per block; 8 groups x 32 lanes, 25 history items each.
// Fused score + browse; outputs feat[256] row to global. (validated r3/r4)
// ---------------------------------------------------------------------------
__global__ __launch_bounds__(256) void k_attn(
    const int* __restrict__ user, const int* __restrict__ item,
    const int* __restrict__ rec,
    const float* __restrict__ tu, const float* __restrict__ t1,
    const float* __restrict__ t2, const float* __restrict__ t3,
    const float* __restrict__ vbuf, float* __restrict__ feat)
{
    __shared__ float s_v[292];
    __shared__ float s_w[E];
    __shared__ __align__(16) float s_feat[256];
    __shared__ float s_part[8][E];
    __shared__ int   s_idx[L * 3];

    const int b = blockIdx.x, t = threadIdx.x;
    const int g = t >> 5, lane = t & 31;

    for (int i = t; i < L * 3; i += 256) s_idx[i] = rec[b * L * 3 + i];
    for (int i = t; i < 289; i += 256) s_v[i] = vbuf[i];
    if (t < E) {                         // q = item_emb -> feat[0..95]
        int f = t >> 5, e = t & 31;
        const float* tab = (f == 0) ? t1 : ((f == 1) ? t2 : t3);
        s_feat[t] = tab[item[b * 3 + f] * 32 + e];
    }
    if (t >= 192) s_feat[t] = tu[(size_t)user[b] * U + (t - 192)];  // user emb
    __syncthreads();

    if (t < E) s_w[t] = s_v[96 + t] + s_feat[t] * s_v[192 + t];
    __syncthreads();

    const float wa = s_w[lane], wb = s_w[32 + lane], wc = s_w[64 + lane];
    float cb = s_feat[lane] * s_v[lane] + s_feat[32 + lane] * s_v[32 + lane]
             + s_feat[64 + lane] * s_v[64 + lane];
    #pragma unroll
    for (int m = 16; m > 0; m >>= 1) cb += __shfl_xor(cb, m);
    cb += s_v[288];

    const int* myidx = s_idx + g * 25 * 3;
    float a0 = 0.f, a1v = 0.f, a2v = 0.f;
    #pragma unroll 5
    for (int i = 0; i < 25; ++i) {
        const int i0 = myidx[i * 3], i1 = myidx[i * 3 + 1], i2 = myidx[i * 3 + 2];
        const float u0 = t1[i0 * 32 + lane];
        const float u1 = t2[i1 * 32 + lane];
        const float u2 = t3[i2 * 32 + lane];
        float p = u0 * wa + u1 * wb + u2 * wc;
        #pragma unroll
        for (int m = 16; m > 0; m >>= 1) p += __shfl_xor(p, m);
        const float sc = (i0 == 0) ? 0.f : (cb + p);
        a0 += sc * u0; a1v += sc * u1; a2v += sc * u2;
    }
    s_part[g][lane]      = a0;
    s_part[g][32 + lane] = a1v;
    s_part[g][64 + lane] = a2v;
    __syncthreads();

    if (t < E) {                         // browse -> feat[96..191]
        float s = 0.f;
        #pragma unroll
        for (int gg = 0; gg < 8; ++gg) s += s_part[gg][t];
        s_feat[96 + t] = s;
    }
    __syncthreads();

    feat[(size_t)b * 256 + t] = s_feat[t];
}

__device__ __forceinline__ void grid_barrier(int* ctr, int t) {
    __syncthreads();                     // all block's prior atomics complete
    if (t == 0) {
        __threadfence();
        atomicAdd(ctr, 1);
        while (__hip_atomic_load(ctr, __ATOMIC_RELAXED,
                                 __HIP_MEMORY_SCOPE_AGENT) < NBLK)
            __builtin_amdgcn_s_sleep(2);
    }
    __syncthreads();
    __threadfence();
}

// ---------------------------------------------------------------------------
// K2: y1 GEMM -> stats1 -> dice1 -> y2 GEMM -> stats2 -> dice2 -> out.
// 256 blocks x 8 rows; y1/y2 stay in LDS across two hand-rolled grid
// barriers (1 block/CU => all co-resident, spin is deadlock-free).
// Cross-block data only via device-scope atomics.
// ---------------------------------------------------------------------------
__global__ __launch_bounds__(256) void k_bcd(
    const float* __restrict__ feat,
    const float* __restrict__ w1, const float* __restrict__ b1,
    const float* __restrict__ a1, const float* __restrict__ g1,
    const float* __restrict__ be1,
    const float* __restrict__ w2, const float* __restrict__ b2,
    const float* __restrict__ a2, const float* __restrict__ g2,
    const float* __restrict__ be2,
    const float* __restrict__ w3, const float* __restrict__ b3,
    float* __restrict__ asum1, float* __restrict__ asq1,
    float* __restrict__ asum2, float* __restrict__ asq2,
    int* __restrict__ bars,
    float* __restrict__ out)
{
    __shared__ __align__(16) float s_f[RB * 256];   // feat; reused as x [RB][H1]
    __shared__ __align__(16) float s_y1[RB][H1];
    __shared__ float s_y2[RB][H2];
    __shared__ float s_c1[H1], s_h1[H1], s_a1[H1];
    __shared__ float s_c2[H2], s_h2[H2], s_a2[H2], s_w3[H2];
    __shared__ float s_p1[3][H2], s_p2[3][H2];

    const int t = threadIdx.x, b0 = blockIdx.x * RB;

    // ---- stage feat tile --------------------------------------------------
    {
        const float4* src = (const float4*)(feat + (size_t)b0 * 256);
        float4* dst = (float4*)s_f;
        dst[t] = src[t];
        dst[t + 256] = src[t + 256];
    }
    __syncthreads();

    // ---- y1 = feat @ w1^T + b1; stats1 partials ---------------------------
    if (t < H1) {
        const float4* wr = (const float4*)(w1 + t * 256);
        float acc[RB];
        const float bj = b1[t];
        #pragma unroll
        for (int bb = 0; bb < RB; ++bb) acc[bb] = bj;
        #pragma unroll 4
        for (int k = 0; k < 64; ++k) {
            const float4 w = wr[k];
            #pragma unroll
            for (int bb = 0; bb < RB; ++bb) {
                const float4 f = ((const float4*)(s_f + bb * 256))[k];
                acc[bb] += w.x * f.x + w.y * f.y + w.z * f.z + w.w * f.w;
            }
        }
        float s1 = 0.f, s2 = 0.f;
        #pragma unroll
        for (int bb = 0; bb < RB; ++bb) {
            s_y1[bb][t] = acc[bb];
            s1 += acc[bb]; s2 += acc[bb] * acc[bb];
        }
        atomicAdd(asum1 + t, s1);
        atomicAdd(asq1 + t, s2);
    }

    grid_barrier(bars, t);               // ---- all stats1 atomics done -----

    // ---- finalize dice-1 scale/shift (redundant per block, cheap) ---------
    if (t < H1) {
        const float al = __hip_atomic_load(asum1 + t, __ATOMIC_RELAXED,
                                           __HIP_MEMORY_SCOPE_AGENT);
        const float aq = __hip_atomic_load(asq1 + t, __ATOMIC_RELAXED,
                                           __HIP_MEMORY_SCOPE_AGENT);
        const float mean = al * (1.f / B);
        float var = (aq - (float)B * mean * mean) * (1.f / (B - 1));
        var = fmaxf(var, 0.f);
        const float a = g1[t] * rsqrtf(var + 1e-8f);
        s_c1[t] = a; s_h1[t] = be1[t] - mean * a; s_a1[t] = a1[t];
    }
    __syncthreads();

    // ---- dice(y1) into s_f (feat no longer needed) ------------------------
    float* s_x = s_f;                    // [RB][H1] packed rr*H1+j
    for (int i = t; i < RB * H1; i += 256) {
        const int rr = i / H1, j = i - rr * H1;
        const float xn = s_y1[rr][j] * s_c1[j] + s_h1[j];
        const float p  = sigf(xn);
        s_x[rr * H1 + j] = xn * (p + s_a1[j] * (1.f - p));
    }
    __syncthreads();

    // ---- y2 = x @ w2^T + b2; stats2 partials (240 active threads) ---------
    {
        const int j = t % H2, rg = t / H2;    // rg 0..2 for t<240
        if (t < 240) {
            const int base = rg * 3;
            const int nb = (rg < 2) ? 3 : 2;  // rows 3/3/2 = 8
            const float4* wr = (const float4*)(w2 + j * H1);
            float acc[3];
            const float bj = b2[j];
            #pragma unroll
            for (int r = 0; r < 3; ++r) acc[r] = bj;
            #pragma unroll 2
            for (int k = 0; k < H1 / 4; ++k) {
                const float4 w = wr[k];
                for (int r = 0; r < nb; ++r) {
                    const float4 x = ((const float4*)(s_x + (base + r) * H1))[k];
                    acc[r] += w.x * x.x + w.y * x.y + w.z * x.z + w.w * x.w;
                }
            }
            float s1 = 0.f, s2 = 0.f;
            for (int r = 0; r < nb; ++r) {
                s_y2[base + r][j] = acc[r];
                s1 += acc[r]; s2 += acc[r] * acc[r];
            }
            s_p1[rg][j] = s1; s_p2[rg][j] = s2;
        }
    }
    __syncthreads();
    if (t < H2) {
        atomicAdd(asum2 + t, s_p1[0][t] + s_p1[1][t] + s_p1[2][t]);
        atomicAdd(asq2 + t, s_p2[0][t] + s_p2[1][t] + s_p2[2][t]);
    }

    grid_barrier(bars + 32, t);          // ---- all stats2 atomics done -----

    // ---- finalize dice-2 scale/shift --------------------------------------
    if (t < H2) {
        const float al = __hip_atomic_load(asum2 + t, __ATOMIC_RELAXED,
                                           __HIP_MEMORY_SCOPE_AGENT);
        const float aq = __hip_atomic_load(asq2 + t, __ATOMIC_RELAXED,
                                           __HIP_MEMORY_SCOPE_AGENT);
        const float mean = al * (1.f / B);
        float var = (aq - (float)B * mean * mean) * (1.f / (B - 1));
        var = fmaxf(var, 0.f);
        const float a = g2[t] * rsqrtf(var + 1e-8f);
        s_c2[t] = a; s_h2[t] = be2[t] - mean * a;
        s_a2[t] = a2[t]; s_w3[t] = w3[t];
    }
    __syncthreads();

    // ---- dice(y2), dot w3, sigmoid: 8 groups x 32 lanes -------------------
    {
        const int g = t >> 5, lane = t & 31;
        float acc = 0.f;
        #pragma unroll
        for (int jj = 0; jj < 3; ++jj) {
            const int j = lane + jj * 32;
            if (j < H2) {
                const float xn = s_y2[g][j] * s_c2[j] + s_h2[j];
                const float p  = sigf(xn);
                acc += xn * (p + s_a2[j] * (1.f - p)) * s_w3[j];
            }
        }
        #pragma unroll
        for (int m = 16; m > 0; m >>= 1) acc += __shfl_xor(acc, m);
        if (lane == 0) out[b0 + g] = sigf(acc + b3[0]);
    }
}

} // namespace

extern "C" void kernel_launch(void* const* d_in, const int* in_sizes, int n_in,
                              void* d_out, int out_size, void* d_ws, size_t ws_size,
                              hipStream_t stream) {
    const int*   user   = (const int*)d_in[0];
    const int*   item   = (const int*)d_in[1];
    const int*   rec    = (const int*)d_in[2];
    const float* tu     = (const float*)d_in[3];
    const float* t1     = (const float*)d_in[4];
    const float* t2     = (const float*)d_in[5];
    const float* t3     = (const float*)d_in[6];
    const float* w_att1 = (const float*)d_in[7];
    const float* b_att1 = (const float*)d_in[8];
    const float* w_att2 = (const float*)d_in[9];
    const float* b_att2 = (const float*)d_in[10];
    const float* w1     = (const float*)d_in[11];
    const float* b1     = (const float*)d_in[12];
    const float* a1     = (const float*)d_in[13];
    const float* g1     = (const float*)d_in[14];
    const float* be1    = (const float*)d_in[15];
    const float* w2     = (const float*)d_in[16];
    const float* b2     = (const float*)d_in[17];
    const float* a2     = (const float*)d_in[18];
    const float* g2     = (const float*)d_in[19];
    const float* be2    = (const float*)d_in[20];
    const float* w3     = (const float*)d_in[21];
    const float* b3     = (const float*)d_in[22];
    float* out = (float*)d_out;

    float* ws    = (float*)d_ws;
    float* asum1 = ws;                      // [0,256)
    float* asq1  = ws + 256;                // [256,512)
    float* asum2 = ws + 512;                // [512,640)
    float* asq2  = ws + 640;                // [640,768)
    int*   bars  = (int*)(ws + 768);        // 64 ints = 2 cache lines
    float* vbuf  = ws + 832;                // [832,1121) pad to 1152
    float* feat  = ws + 1152;               // B*256

    hipLaunchKernelGGL(k_pre,  dim3(1),    dim3(768), 0, stream,
                       w_att1, b_att1, w_att2, b_att2, ws, bars, vbuf);
    hipLaunchKernelGGL(k_attn, dim3(B),    dim3(256), 0, stream,
                       user, item, rec, tu, t1, t2, t3, vbuf, feat);
    hipLaunchKernelGGL(k_bcd,  dim3(NBLK), dim3(256), 0, stream,
                       feat, w1, b1, a1, g1, be1, w2, b2, a2, g2, be2, w3, b3,
                       asum1, asq1, asum2, asq2, bars, out);
}

// Round 7
// 91.311 us; speedup vs baseline: 1.2808x; 1.2808x over previous
//
#include <hip/hip_runtime.h>
#include <math.h>

namespace {

constexpr int B   = 2048;
constexpr int L   = 200;
constexpr int E   = 96;    // 3 * D_FEAT
constexpr int U   = 64;
constexpr int NA  = 36;    // HID_ATT
constexpr int H1  = 200;
constexpr int H2  = 80;
constexpr int RB  = 8;     // rows per block for gemm1/mlp/final
constexpr int NBLK = B / RB;   // 256

__device__ __forceinline__ float sigf(float x) {
    return 1.0f / (1.0f + __expf(-x));
}

// VALU-only partial reduce: 4 DPP adds cover xor1/xor2/xor7/xor15 within each
// 16-lane row pair; one ds_swizzle (shfl_xor 16) finishes the 32-lane group.
template <int CTRL>
__device__ __forceinline__ float dppadd(float x) {
    int v = __builtin_amdgcn_update_dpp(0, __builtin_bit_cast(int, x),
                                        CTRL, 0xf, 0xf, true);
    return x + __builtin_bit_cast(float, v);
}
__device__ __forceinline__ float grp32_sum(float p) {
    p = dppadd<0xB1>(p);    // quad_perm [1,0,3,2]  : lane ^ 1
    p = dppadd<0x4E>(p);    // quad_perm [2,3,0,1]  : lane ^ 2
    p = dppadd<0x141>(p);   // row_half_mirror      : lane ^ 7 (other quad)
    p = dppadd<0x140>(p);   // row_mirror           : lane ^ 15 (other 8-group)
    p += __shfl_xor(p, 16); // cross the 16-lane rows within the 32-group
    return p;
}

// ---------------------------------------------------------------------------
// K1: one batch row per block. Per-block fold of the linear attention MLP
// (w_att2 @ w_att1 -> 289 floats), then 8 groups x 32 lanes x 25 items of
// fused score+browse. idx packed as int4 -> 1 ds_read_b128 per item.
// ---------------------------------------------------------------------------
__global__ __launch_bounds__(256) void k_attn(
    const int* __restrict__ user, const int* __restrict__ item,
    const int* __restrict__ rec,
    const float* __restrict__ tu, const float* __restrict__ t1,
    const float* __restrict__ t2, const float* __restrict__ t3,
    const float* __restrict__ w_att1, const float* __restrict__ b_att1,
    const float* __restrict__ w_att2, const float* __restrict__ b_att2,
    float* __restrict__ feat)
{
    __shared__ float s_v[292];
    __shared__ __align__(16) float s_feat[256];
    __shared__ float s_part[8][E];
    __shared__ __align__(16) int4 s_idx4[L];

    const int b = blockIdx.x, t = threadIdx.x;
    const int g = t >> 5, lane = t & 31;

    // ---- fold: s_v[0..95]=v1+v3 | [96..191]=v2-v3 | [192..287]=v4 | [288]=c
    for (int j = t; j < 289; j += 256) {
        float s;
        if (j < 96) {
            s = 0.f;
            #pragma unroll
            for (int k = 0; k < NA; ++k)
                s += w_att2[k] * (w_att1[k * 384 + j] + w_att1[k * 384 + 192 + j]);
        } else if (j < 192) {
            const int e = j - 96; s = 0.f;
            #pragma unroll
            for (int k = 0; k < NA; ++k)
                s += w_att2[k] * (w_att1[k * 384 + 96 + e] - w_att1[k * 384 + 192 + e]);
        } else if (j < 288) {
            const int e = j - 192; s = 0.f;
            #pragma unroll
            for (int k = 0; k < NA; ++k)
                s += w_att2[k] * w_att1[k * 384 + 288 + e];
        } else {
            s = b_att2[0];
            #pragma unroll
            for (int k = 0; k < NA; ++k) s += w_att2[k] * b_att1[k];
        }
        s_v[j] = s;
    }

    // ---- stage idx (padded to int4), q, user emb ---------------------------
    {
        int* si = (int*)s_idx4;
        for (int i = t; i < L * 3; i += 256) {
            const int v = rec[(size_t)b * L * 3 + i];
            si[(i / 3) * 4 + (i % 3)] = v;
        }
    }
    if (t < E) {                          // q = item_emb -> feat[0..95]
        const int f = t >> 5, e = t & 31;
        const float* tab = (f == 0) ? t1 : ((f == 1) ? t2 : t3);
        s_feat[t] = tab[item[b * 3 + f] * 32 + e];
    }
    if (t >= 192) s_feat[t] = tu[(size_t)user[b] * U + (t - 192)];
    __syncthreads();

    // per-lane score weights + row constant
    const float q0 = s_feat[lane], q1 = s_feat[32 + lane], q2 = s_feat[64 + lane];
    const float wa = s_v[96 + lane]  + q0 * s_v[192 + lane];
    const float wb = s_v[128 + lane] + q1 * s_v[224 + lane];
    const float wc = s_v[160 + lane] + q2 * s_v[256 + lane];
    float cb = q0 * s_v[lane] + q1 * s_v[32 + lane] + q2 * s_v[64 + lane];
    cb = grp32_sum(cb) + s_v[288];

    // ---- fused score + browse: 25 items per group --------------------------
    float a0 = 0.f, a1v = 0.f, a2v = 0.f;
    #pragma unroll 5
    for (int i = 0; i < 25; ++i) {
        const int4 iv = s_idx4[g * 25 + i];
        const float u0 = t1[iv.x * 32 + lane];
        const float u1 = t2[iv.y * 32 + lane];
        const float u2 = t3[iv.z * 32 + lane];
        float p = u0 * wa + u1 * wb + u2 * wc;
        p = grp32_sum(p);
        const float sc = (iv.x == 0) ? 0.f : (cb + p);
        a0 += sc * u0; a1v += sc * u1; a2v += sc * u2;
    }
    s_part[g][lane]      = a0;
    s_part[g][32 + lane] = a1v;
    s_part[g][64 + lane] = a2v;
    __syncthreads();

    if (t < E) {                          // browse -> feat[96..191]
        float s = 0.f;
        #pragma unroll
        for (int gg = 0; gg < 8; ++gg) s += s_part[gg][t];
        s_feat[96 + t] = s;
    }
    __syncthreads();

    feat[(size_t)b * 256 + t] = s_feat[t];
}

// ---------------------------------------------------------------------------
// K2: y1 = feat @ w1^T + b1 (8 rows/block); per-block column partials stored
// to part1[blk][0..199]=sum, [200..399]=sumsq. No atomics.
// ---------------------------------------------------------------------------
__global__ __launch_bounds__(256) void k_gemm1(
    const float* __restrict__ feat,
    const float* __restrict__ w1, const float* __restrict__ b1,
    float* __restrict__ y1, float* __restrict__ part1)
{
    __shared__ __align__(16) float s_f[RB * 256];
    const int t = threadIdx.x, b0 = blockIdx.x * RB;

    const float4* src = (const float4*)(feat + (size_t)b0 * 256);
    float4* dst = (float4*)s_f;
    dst[t] = src[t];
    dst[t + 256] = src[t + 256];
    __syncthreads();

    if (t < H1) {
        const float4* wr = (const float4*)(w1 + t * 256);
        float acc[RB];
        const float bj = b1[t];
        #pragma unroll
        for (int bb = 0; bb < RB; ++bb) acc[bb] = bj;
        #pragma unroll 4
        for (int k = 0; k < 64; ++k) {
            const float4 w = wr[k];
            #pragma unroll
            for (int bb = 0; bb < RB; ++bb) {
                const float4 f = ((const float4*)(s_f + bb * 256))[k];
                acc[bb] += w.x * f.x + w.y * f.y + w.z * f.z + w.w * f.w;
            }
        }
        float s1 = 0.f, s2 = 0.f;
        #pragma unroll
        for (int bb = 0; bb < RB; ++bb) {
            y1[(size_t)(b0 + bb) * H1 + t] = acc[bb];
            s1 += acc[bb]; s2 += acc[bb] * acc[bb];
        }
        part1[(size_t)blockIdx.x * 400 + t]       = s1;
        part1[(size_t)blockIdx.x * 400 + 200 + t] = s2;
    }
}

// ---------------------------------------------------------------------------
// K3: redundant part1 reduce -> dice1 scale/shift; dice(y1); y2 = x @ w2^T;
// per-block part2 stores.
// ---------------------------------------------------------------------------
__global__ __launch_bounds__(256) void k_mlp(
    const float* __restrict__ y1, const float* __restrict__ part1,
    const float* __restrict__ a1, const float* __restrict__ g1,
    const float* __restrict__ be1,
    const float* __restrict__ w2, const float* __restrict__ b2,
    float* __restrict__ y2, float* __restrict__ part2)
{
    __shared__ float s_c1[H1], s_h1[H1], s_al[H1];
    __shared__ __align__(16) float s_x[RB][H1];
    __shared__ float s_p1[3][H2], s_p2[3][H2];
    const int t = threadIdx.x, b0 = blockIdx.x * RB;

    // ---- reduce 256 partial rows (redundant per block, coalesced) ----------
    if (t < H1) {
        float s = 0.f, q = 0.f;
        #pragma unroll 4
        for (int p = 0; p < NBLK; ++p) {
            s += part1[(size_t)p * 400 + t];
            q += part1[(size_t)p * 400 + 200 + t];
        }
        const float mean = s * (1.f / B);
        float var = (q - (float)B * mean * mean) * (1.f / (B - 1));
        var = fmaxf(var, 0.f);
        const float a = g1[t] * rsqrtf(var + 1e-8f);
        s_c1[t] = a; s_h1[t] = be1[t] - mean * a; s_al[t] = a1[t];
    }
    __syncthreads();

    for (int i = t; i < RB * H1; i += 256) {
        const int j = i % H1;
        const float xn = y1[(size_t)b0 * H1 + i] * s_c1[j] + s_h1[j];
        const float p  = sigf(xn);
        s_x[i / H1][j] = xn * (p + s_al[j] * (1.f - p));
    }
    __syncthreads();

    const int j = t % H2, rg = t / H2;    // rg 0..2 for t<240
    if (t < 240) {
        const int base = rg * 3;
        const int nb = (rg < 2) ? 3 : 2;  // rows 3/3/2 = 8
        const float4* wr = (const float4*)(w2 + j * H1);
        float acc[3];
        const float bj = b2[j];
        #pragma unroll
        for (int r = 0; r < 3; ++r) acc[r] = bj;
        #pragma unroll 2
        for (int k = 0; k < H1 / 4; ++k) {
            const float4 w = wr[k];
            for (int r = 0; r < nb; ++r) {
                const float4 x = ((const float4*)s_x[base + r])[k];
                acc[r] += w.x * x.x + w.y * x.y + w.z * x.z + w.w * x.w;
            }
        }
        float s1 = 0.f, s2 = 0.f;
        for (int r = 0; r < nb; ++r) {
            y2[(size_t)(b0 + base + r) * H2 + j] = acc[r];
            s1 += acc[r]; s2 += acc[r] * acc[r];
        }
        s_p1[rg][j] = s1; s_p2[rg][j] = s2;
    }
    __syncthreads();
    if (t < H2) {
        part2[(size_t)blockIdx.x * 160 + t]      = s_p1[0][t] + s_p1[1][t] + s_p1[2][t];
        part2[(size_t)blockIdx.x * 160 + 80 + t] = s_p2[0][t] + s_p2[1][t] + s_p2[2][t];
    }
}

// ---------------------------------------------------------------------------
// K4: redundant part2 reduce -> dice2 scale/shift; dice(y2); dot w3; sigmoid.
// ---------------------------------------------------------------------------
__global__ __launch_bounds__(256) void k_final(
    const float* __restrict__ y2, const float* __restrict__ part2,
    const float* __restrict__ a2, const float* __restrict__ g2,
    const float* __restrict__ be2,
    const float* __restrict__ w3, const float* __restrict__ b3,
    float* __restrict__ out)
{
    __shared__ float s_c[H2], s_s[H2], s_aw[H2], s_w3[H2];
    const int t = threadIdx.x, b0 = blockIdx.x * RB;
    const int g = t >> 5, lane = t & 31;

    if (t < H2) {
        float s = 0.f, q = 0.f;
        #pragma unroll 4
        for (int p = 0; p < NBLK; ++p) {
            s += part2[(size_t)p * 160 + t];
            q += part2[(size_t)p * 160 + 80 + t];
        }
        const float mean = s * (1.f / B);
        float var = (q - (float)B * mean * mean) * (1.f / (B - 1));
        var = fmaxf(var, 0.f);
        const float a = g2[t] * rsqrtf(var + 1e-8f);
        s_c[t] = a; s_s[t] = be2[t] - mean * a;
        s_aw[t] = a2[t]; s_w3[t] = w3[t];
    }
    __syncthreads();

    const int r = b0 + g;
    float acc = 0.f;
    #pragma unroll
    for (int jj = 0; jj < 3; ++jj) {
        const int j = lane + jj * 32;
        if (j < H2) {
            const float xn = y2[(size_t)r * H2 + j] * s_c[j] + s_s[j];
            const float p  = sigf(xn);
            acc += xn * (p + s_aw[j] * (1.f - p)) * s_w3[j];
        }
    }
    acc = grp32_sum(acc);
    if (lane == 0) out[r] = sigf(acc + b3[0]);
}

} // namespace

extern "C" void kernel_launch(void* const* d_in, const int* in_sizes, int n_in,
                              void* d_out, int out_size, void* d_ws, size_t ws_size,
                              hipStream_t stream) {
    const int*   user   = (const int*)d_in[0];
    const int*   item   = (const int*)d_in[1];
    const int*   rec    = (const int*)d_in[2];
    const float* tu     = (const float*)d_in[3];
    const float* t1     = (const float*)d_in[4];
    const float* t2     = (const float*)d_in[5];
    const float* t3     = (const float*)d_in[6];
    const float* w_att1 = (const float*)d_in[7];
    const float* b_att1 = (const float*)d_in[8];
    const float* w_att2 = (const float*)d_in[9];
    const float* b_att2 = (const float*)d_in[10];
    const float* w1     = (const float*)d_in[11];
    const float* b1     = (const float*)d_in[12];
    const float* a1     = (const float*)d_in[13];
    const float* g1     = (const float*)d_in[14];
    const float* be1    = (const float*)d_in[15];
    const float* w2     = (const float*)d_in[16];
    const float* b2     = (const float*)d_in[17];
    const float* a2     = (const float*)d_in[18];
    const float* g2     = (const float*)d_in[19];
    const float* be2    = (const float*)d_in[20];
    const float* w3     = (const float*)d_in[21];
    const float* b3     = (const float*)d_in[22];
    float* out = (float*)d_out;

    float* ws    = (float*)d_ws;
    float* part1 = ws;                           // 256*400 = 102400
    float* part2 = part1 + (size_t)NBLK * 400;   // 256*160 = 40960
    float* feat  = part2 + (size_t)NBLK * 160;   // B*256
    float* y1    = feat + (size_t)B * 256;       // B*H1
    float* y2    = y1 + (size_t)B * H1;          // B*H2

    hipLaunchKernelGGL(k_attn,  dim3(B),    dim3(256), 0, stream,
                       user, item, rec, tu, t1, t2, t3,
                       w_att1, b_att1, w_att2, b_att2, feat);
    hipLaunchKernelGGL(k_gemm1, dim3(NBLK), dim3(256), 0, stream,
                       feat, w1, b1, y1, part1);
    hipLaunchKernelGGL(k_mlp,   dim3(NBLK), dim3(256), 0, stream,
                       y1, part1, a1, g1, be1, w2, b2, y2, part2);
    hipLaunchKernelGGL(k_final, dim3(NBLK), dim3(256), 0, stream,
                       y2, part2, a2, g2, be2, w3, b3, out);
}

// Round 8
// 60.111 us; speedup vs baseline: 1.9456x; 1.5190x over previous
//
#include <hip/hip_runtime.h>
#include <math.h>

namespace {

constexpr int B   = 2048;
constexpr int L   = 200;
constexpr int E   = 96;    // 3 * D_FEAT
constexpr int U   = 64;
constexpr int NA  = 36;    // HID_ATT
constexpr int H1  = 200;
constexpr int H2  = 80;
constexpr int RB  = 8;     // rows per block for gemm1/mlp/final
constexpr int NBLK = B / RB;   // 256

__device__ __forceinline__ float sigf(float x) {
    return 1.0f / (1.0f + __expf(-x));
}

// VALU-only partial reduce: 4 DPP adds + one shfl_xor(16).
template <int CTRL>
__device__ __forceinline__ float dppadd(float x) {
    int v = __builtin_amdgcn_update_dpp(0, __builtin_bit_cast(int, x),
                                        CTRL, 0xf, 0xf, true);
    return x + __builtin_bit_cast(float, v);
}
__device__ __forceinline__ float grp32_sum(float p) {
    p = dppadd<0xB1>(p);    // lane ^ 1
    p = dppadd<0x4E>(p);    // lane ^ 2
    p = dppadd<0x141>(p);   // row_half_mirror (^7)
    p = dppadd<0x140>(p);   // row_mirror (^15)
    p += __shfl_xor(p, 16);
    return p;
}

// ---------------------------------------------------------------------------
// K1: one batch row per block. Per-block fold of the linear attention MLP,
// then 8 groups x 32 lanes x 25 items of fused score+browse.
// ---------------------------------------------------------------------------
__global__ __launch_bounds__(256) void k_attn(
    const int* __restrict__ user, const int* __restrict__ item,
    const int* __restrict__ rec,
    const float* __restrict__ tu, const float* __restrict__ t1,
    const float* __restrict__ t2, const float* __restrict__ t3,
    const float* __restrict__ w_att1, const float* __restrict__ b_att1,
    const float* __restrict__ w_att2, const float* __restrict__ b_att2,
    float* __restrict__ feat)
{
    __shared__ float s_v[292];
    __shared__ __align__(16) float s_feat[256];
    __shared__ float s_part[8][E];
    __shared__ __align__(16) int4 s_idx4[L];

    const int b = blockIdx.x, t = threadIdx.x;
    const int g = t >> 5, lane = t & 31;

    // ---- fold: s_v[0..95]=v1+v3 | [96..191]=v2-v3 | [192..287]=v4 | [288]=c
    for (int j = t; j < 289; j += 256) {
        float s;
        if (j < 96) {
            s = 0.f;
            #pragma unroll
            for (int k = 0; k < NA; ++k)
                s += w_att2[k] * (w_att1[k * 384 + j] + w_att1[k * 384 + 192 + j]);
        } else if (j < 192) {
            const int e = j - 96; s = 0.f;
            #pragma unroll
            for (int k = 0; k < NA; ++k)
                s += w_att2[k] * (w_att1[k * 384 + 96 + e] - w_att1[k * 384 + 192 + e]);
        } else if (j < 288) {
            const int e = j - 192; s = 0.f;
            #pragma unroll
            for (int k = 0; k < NA; ++k)
                s += w_att2[k] * w_att1[k * 384 + 288 + e];
        } else {
            s = b_att2[0];
            #pragma unroll
            for (int k = 0; k < NA; ++k) s += w_att2[k] * b_att1[k];
        }
        s_v[j] = s;
    }

    // ---- stage idx (padded to int4), q, user emb ---------------------------
    {
        int* si = (int*)s_idx4;
        for (int i = t; i < L * 3; i += 256) {
            const int v = rec[(size_t)b * L * 3 + i];
            si[(i / 3) * 4 + (i % 3)] = v;
        }
    }
    if (t < E) {                          // q = item_emb -> feat[0..95]
        const int f = t >> 5, e = t & 31;
        const float* tab = (f == 0) ? t1 : ((f == 1) ? t2 : t3);
        s_feat[t] = tab[item[b * 3 + f] * 32 + e];
    }
    if (t >= 192) s_feat[t] = tu[(size_t)user[b] * U + (t - 192)];
    __syncthreads();

    const float q0 = s_feat[lane], q1 = s_feat[32 + lane], q2 = s_feat[64 + lane];
    const float wa = s_v[96 + lane]  + q0 * s_v[192 + lane];
    const float wb = s_v[128 + lane] + q1 * s_v[224 + lane];
    const float wc = s_v[160 + lane] + q2 * s_v[256 + lane];
    float cb = q0 * s_v[lane] + q1 * s_v[32 + lane] + q2 * s_v[64 + lane];
    cb = grp32_sum(cb) + s_v[288];

    float a0 = 0.f, a1v = 0.f, a2v = 0.f;
    #pragma unroll 5
    for (int i = 0; i < 25; ++i) {
        const int4 iv = s_idx4[g * 25 + i];
        const float u0 = t1[iv.x * 32 + lane];
        const float u1 = t2[iv.y * 32 + lane];
        const float u2 = t3[iv.z * 32 + lane];
        float p = u0 * wa + u1 * wb + u2 * wc;
        p = grp32_sum(p);
        const float sc = (iv.x == 0) ? 0.f : (cb + p);
        a0 += sc * u0; a1v += sc * u1; a2v += sc * u2;
    }
    s_part[g][lane]      = a0;
    s_part[g][32 + lane] = a1v;
    s_part[g][64 + lane] = a2v;
    __syncthreads();

    if (t < E) {
        float s = 0.f;
        #pragma unroll
        for (int gg = 0; gg < 8; ++gg) s += s_part[gg][t];
        s_feat[96 + t] = s;
    }
    __syncthreads();

    feat[(size_t)b * 256 + t] = s_feat[t];
}

// ---------------------------------------------------------------------------
// K2: y1 = feat @ w1^T + b1 (8 rows/block); per-block column partials to
// part1[blk][0..199]=sum, [200..399]=sumsq. No atomics.
// ---------------------------------------------------------------------------
__global__ __launch_bounds__(256) void k_gemm1(
    const float* __restrict__ feat,
    const float* __restrict__ w1, const float* __restrict__ b1,
    float* __restrict__ y1, float* __restrict__ part1)
{
    __shared__ __align__(16) float s_f[RB * 256];
    const int t = threadIdx.x, b0 = blockIdx.x * RB;

    const float4* src = (const float4*)(feat + (size_t)b0 * 256);
    float4* dst = (float4*)s_f;
    dst[t] = src[t];
    dst[t + 256] = src[t + 256];
    __syncthreads();

    if (t < H1) {
        const float4* wr = (const float4*)(w1 + t * 256);
        float acc[RB];
        const float bj = b1[t];
        #pragma unroll
        for (int bb = 0; bb < RB; ++bb) acc[bb] = bj;
        #pragma unroll 4
        for (int k = 0; k < 64; ++k) {
            const float4 w = wr[k];
            #pragma unroll
            for (int bb = 0; bb < RB; ++bb) {
                const float4 f = ((const float4*)(s_f + bb * 256))[k];
                acc[bb] += w.x * f.x + w.y * f.y + w.z * f.z + w.w * f.w;
            }
        }
        float s1 = 0.f, s2 = 0.f;
        #pragma unroll
        for (int bb = 0; bb < RB; ++bb) {
            y1[(size_t)(b0 + bb) * H1 + t] = acc[bb];
            s1 += acc[bb]; s2 += acc[bb] * acc[bb];
        }
        part1[(size_t)blockIdx.x * 400 + t]       = s1;
        part1[(size_t)blockIdx.x * 400 + 200 + t] = s2;
    }
}

// ---------------------------------------------------------------------------
// K2b/K3b: finalize column stats from partials. One block per column;
// thread t reads partial row t (2 loads), LDS tree reduce, write sc/sh.
// ---------------------------------------------------------------------------
template <int NCOL, int STRIDE>
__global__ __launch_bounds__(256) void k_stats(
    const float* __restrict__ part, const float* __restrict__ g,
    const float* __restrict__ be,
    float* __restrict__ sc, float* __restrict__ sh)
{
    __shared__ float rs[256], rq[256];
    const int j = blockIdx.x, t = threadIdx.x;
    rs[t] = part[(size_t)t * STRIDE + j];
    rq[t] = part[(size_t)t * STRIDE + NCOL + j];
    __syncthreads();
    #pragma unroll
    for (int o = 128; o > 0; o >>= 1) {
        if (t < o) { rs[t] += rs[t + o]; rq[t] += rq[t + o]; }
        __syncthreads();
    }
    if (t == 0) {
        const float mean = rs[0] * (1.f / B);
        float var = (rq[0] - (float)B * mean * mean) * (1.f / (B - 1));
        var = fmaxf(var, 0.f);
        const float a = g[j] * rsqrtf(var + 1e-8f);
        sc[j] = a;
        sh[j] = be[j] - mean * a;
    }
}

// ---------------------------------------------------------------------------
// K3: dice(y1) -> y2 = x @ w2^T + b2 (8 rows/block); part2 stores.
// ---------------------------------------------------------------------------
__global__ __launch_bounds__(256) void k_mlp(
    const float* __restrict__ y1,
    const float* __restrict__ sc1, const float* __restrict__ sh1,
    const float* __restrict__ a1,
    const float* __restrict__ w2, const float* __restrict__ b2,
    float* __restrict__ y2, float* __restrict__ part2)
{
    __shared__ float s_c1[H1], s_h1[H1], s_al[H1];
    __shared__ __align__(16) float s_x[RB][H1];
    __shared__ float s_p1[3][H2], s_p2[3][H2];
    const int t = threadIdx.x, b0 = blockIdx.x * RB;

    if (t < H1) { s_c1[t] = sc1[t]; s_h1[t] = sh1[t]; s_al[t] = a1[t]; }
    __syncthreads();

    for (int i = t; i < RB * H1; i += 256) {
        const int j = i % H1;
        const float xn = y1[(size_t)b0 * H1 + i] * s_c1[j] + s_h1[j];
        const float p  = sigf(xn);
        s_x[i / H1][j] = xn * (p + s_al[j] * (1.f - p));
    }
    __syncthreads();

    const int j = t % H2, rg = t / H2;    // rg 0..2 for t<240
    if (t < 240) {
        const int base = rg * 3;
        const int nb = (rg < 2) ? 3 : 2;  // rows 3/3/2 = 8
        const float4* wr = (const float4*)(w2 + j * H1);
        float acc[3];
        const float bj = b2[j];
        #pragma unroll
        for (int r = 0; r < 3; ++r) acc[r] = bj;
        #pragma unroll 2
        for (int k = 0; k < H1 / 4; ++k) {
            const float4 w = wr[k];
            for (int r = 0; r < nb; ++r) {
                const float4 x = ((const float4*)s_x[base + r])[k];
                acc[r] += w.x * x.x + w.y * x.y + w.z * x.z + w.w * x.w;
            }
        }
        float s1 = 0.f, s2 = 0.f;
        for (int r = 0; r < nb; ++r) {
            y2[(size_t)(b0 + base + r) * H2 + j] = acc[r];
            s1 += acc[r]; s2 += acc[r] * acc[r];
        }
        s_p1[rg][j] = s1; s_p2[rg][j] = s2;
    }
    __syncthreads();
    if (t < H2) {
        part2[(size_t)blockIdx.x * 160 + t]      = s_p1[0][t] + s_p1[1][t] + s_p1[2][t];
        part2[(size_t)blockIdx.x * 160 + 80 + t] = s_p2[0][t] + s_p2[1][t] + s_p2[2][t];
    }
}

// ---------------------------------------------------------------------------
// K4: dice(y2), dot w3, sigmoid. 8 rows/block, 32 lanes per row.
// ---------------------------------------------------------------------------
__global__ __launch_bounds__(256) void k_final(
    const float* __restrict__ y2,
    const float* __restrict__ sc2, const float* __restrict__ sh2,
    const float* __restrict__ a2,
    const float* __restrict__ w3, const float* __restrict__ b3,
    float* __restrict__ out)
{
    __shared__ float s_c[H2], s_s[H2], s_aw[H2], s_w3[H2];
    const int t = threadIdx.x, b0 = blockIdx.x * RB;
    const int g = t >> 5, lane = t & 31;

    if (t < H2) {
        s_c[t] = sc2[t]; s_s[t] = sh2[t];
        s_aw[t] = a2[t]; s_w3[t] = w3[t];
    }
    __syncthreads();

    const int r = b0 + g;
    float acc = 0.f;
    #pragma unroll
    for (int jj = 0; jj < 3; ++jj) {
        const int j = lane + jj * 32;
        if (j < H2) {
            const float xn = y2[(size_t)r * H2 + j] * s_c[j] + s_s[j];
            const float p  = sigf(xn);
            acc += xn * (p + s_aw[j] * (1.f - p)) * s_w3[j];
        }
    }
    acc = grp32_sum(acc);
    if (lane == 0) out[r] = sigf(acc + b3[0]);
}

} // namespace

extern "C" void kernel_launch(void* const* d_in, const int* in_sizes, int n_in,
                              void* d_out, int out_size, void* d_ws, size_t ws_size,
                              hipStream_t stream) {
    const int*   user   = (const int*)d_in[0];
    const int*   item   = (const int*)d_in[1];
    const int*   rec    = (const int*)d_in[2];
    const float* tu     = (const float*)d_in[3];
    const float* t1     = (const float*)d_in[4];
    const float* t2     = (const float*)d_in[5];
    const float* t3     = (const float*)d_in[6];
    const float* w_att1 = (const float*)d_in[7];
    const float* b_att1 = (const float*)d_in[8];
    const float* w_att2 = (const float*)d_in[9];
    const float* b_att2 = (const float*)d_in[10];
    const float* w1     = (const float*)d_in[11];
    const float* b1     = (const float*)d_in[12];
    const float* a1     = (const float*)d_in[13];
    const float* g1     = (const float*)d_in[14];
    const float* be1    = (const float*)d_in[15];
    const float* w2     = (const float*)d_in[16];
    const float* b2     = (const float*)d_in[17];
    const float* a2     = (const float*)d_in[18];
    const float* g2     = (const float*)d_in[19];
    const float* be2    = (const float*)d_in[20];
    const float* w3     = (const float*)d_in[21];
    const float* b3     = (const float*)d_in[22];
    float* out = (float*)d_out;

    float* ws    = (float*)d_ws;
    float* part1 = ws;                           // 256*400
    float* part2 = part1 + (size_t)NBLK * 400;   // 256*160
    float* sc1   = part2 + (size_t)NBLK * 160;   // 256 (200 used)
    float* sh1   = sc1 + 256;                    // 256
    float* sc2   = sh1 + 256;                    // 128 (80 used)
    float* sh2   = sc2 + 128;                    // 128
    float* feat  = sh2 + 128;                    // B*256
    float* y1    = feat + (size_t)B * 256;       // B*H1
    float* y2    = y1 + (size_t)B * H1;          // B*H2

    hipLaunchKernelGGL(k_attn,  dim3(B),    dim3(256), 0, stream,
                       user, item, rec, tu, t1, t2, t3,
                       w_att1, b_att1, w_att2, b_att2, feat);
    hipLaunchKernelGGL(k_gemm1, dim3(NBLK), dim3(256), 0, stream,
                       feat, w1, b1, y1, part1);
    hipLaunchKernelGGL((k_stats<H1, 400>), dim3(H1), dim3(256), 0, stream,
                       part1, g1, be1, sc1, sh1);
    hipLaunchKernelGGL(k_mlp,   dim3(NBLK), dim3(256), 0, stream,
                       y1, sc1, sh1, a1, w2, b2, y2, part2);
    hipLaunchKernelGGL((k_stats<H2, 160>), dim3(H2), dim3(256), 0, stream,
                       part2, g2, be2, sc2, sh2);
    hipLaunchKernelGGL(k_final, dim3(NBLK), dim3(256), 0, stream,
                       y2, sc2, sh2, a2, w3, b3, out);
}